// Round 24
// baseline (287.541 us; speedup 1.0000x reference)
//
#include <hip/hip_runtime.h>

#define S_LEN 2048
#define HID   2048
#define NHEAD 16
#define HDIM  128
#define BATCH 2
#define KDIM  2048

using bf16x8  = __attribute__((ext_vector_type(8))) short;
using f32x4   = __attribute__((ext_vector_type(4))) float;
using f32x16  = __attribute__((ext_vector_type(16))) float;
using short4v = __attribute__((ext_vector_type(4))) short;
using uint4v  = __attribute__((ext_vector_type(4))) unsigned;

__device__ __forceinline__ short f2bf(float f) {
  union { float f; unsigned u; } v; v.f = f;
  unsigned r = v.u + 0x7fffu + ((v.u >> 16) & 1u);
  return (short)(r >> 16);
}
__device__ __forceinline__ float bf2f(short s) {
  union { unsigned u; float f; } v;
  v.u = ((unsigned)(unsigned short)s) << 16;
  return v.f;
}

// async global->LDS, 16B per lane. LDS dest must be wave-uniform base + lane*16.
__device__ __forceinline__ void gl_lds16(const void* g, void* l) {
  __builtin_amdgcn_global_load_lds(
      (const __attribute__((address_space(1))) void*)g,
      (__attribute__((address_space(3))) void*)l, 16, 0, 0);
}

// ---------------- convert: hs, wq, wk, wv, wo  f32 -> bf16 -------------------
__global__ __launch_bounds__(256)
void convert_all(const float* __restrict__ hs, const float* __restrict__ wq,
                 const float* __restrict__ wk, const float* __restrict__ wv,
                 const float* __restrict__ wo,
                 short* __restrict__ hsb, short* __restrict__ wqkv,
                 short* __restrict__ wob)
{
  const int base = blockIdx.x * 256 + threadIdx.x;
#pragma unroll
  for (int it = 0; it < 6; ++it) {
    int j = base + it * 524288;
    const float* src; short* dst;
    if (j < 1048576)      { src = hs; dst = hsb; }
    else if (j < 1572864) { j -= 1048576; src = wq; dst = wqkv; }
    else if (j < 2097152) { j -= 1572864; src = wk; dst = wqkv + 4194304; }
    else if (j < 2621440) { j -= 2097152; src = wv; dst = wqkv + 8388608; }
    else                  { j -= 2621440; src = wo; dst = wob; }
    f32x4 a = ((const f32x4*)src)[2 * j];
    f32x4 b = ((const f32x4*)src)[2 * j + 1];
    bf16x8 o;
    o[0]=f2bf(a[0]); o[1]=f2bf(a[1]); o[2]=f2bf(a[2]); o[3]=f2bf(a[3]);
    o[4]=f2bf(b[0]); o[5]=f2bf(b[1]); o[6]=f2bf(b[2]); o[7]=f2bf(b[3]);
    ((bf16x8*)dst)[j] = o;
  }
}

// ---------------- 8-phase 256x256 QKV GEMM (m201 template port) --------------
// BM=BN=256, BK=64, 512 thr = 8 waves (2M x 4N), per-wave 128x64 (acc[8][4]).
// dbuf LDS 128 KiB. Per K-tile: 4 phases, each = ONE 16-MFMA C-quadrant with
// 2 barriers; stage spread: ph0 stages A(T+1) (4 loads), ph1 stages B(T+1).
// Counted vmcnt(4) ONLY at ph0 (A(T+1) stays in flight; B(T+1) has 3 phases
// of cover), vmcnt(0) only at the last tile. Raw s_barrier (never
// __syncthreads: it would drain vmcnt). sched_barrier(0) after top / before
// bottom barriers pins ds_reads into their validated region. Slot-reuse
// audit: stage(T+1 -> nxt) issues after T-1 ph3's post-MFMA bottom barrier,
// hence after ALL waves' reads of slot nxt completed. Chunk-XOR involution
// (r11-proven, 0 conflicts): linear gl_lds dest + inverse-swizzled source.
__global__ __launch_bounds__(512)
void gemm256_8p(const short* __restrict__ A, const short* __restrict__ B,
                const float* __restrict__ bq, const float* __restrict__ bkb,
                const float* __restrict__ bv,
                short* __restrict__ Qo, short* __restrict__ Ko,
                short* __restrict__ Vo)
{
  __shared__ __align__(16) short LA[2 * 16384];   // 2 x [256][64]
  __shared__ __align__(16) short LB[2 * 16384];   // 2 x [256][64]
  const int tid  = threadIdx.x;
  const int lane = tid & 63, wave = tid >> 6;
  const int ln = lane & 15, g = lane >> 4;
  const int wm = wave >> 2, wn = wave & 3;
  const int m0 = blockIdx.x * 256, n0 = blockIdx.y * 256;

  const int srow   = tid >> 3;                    // 0..63
  const int schunk = (tid & 7) ^ (srow & 7);
  const short* aS = A + (size_t)(m0 + srow) * KDIM + schunk * 8;
  const short* bS = B + (size_t)(n0 + srow) * KDIM + schunk * 8;

  const int rAb = wm * 128 + ln;                  // + mf*16 (16 = 0 mod 8)
  const int rBb = wn * 64 + ln;                   // + nf*16
  const int ax = rAb & 7, bx2 = rBb & 7;

  f32x4 acc[8][4] = {};

  auto stA2 = [&](int T, int s, int h) {          // one 128-row A half: 2 loads
    gl_lds16(aS + (size_t)(h * 128)      * KDIM + T * 64,
             &LA[s * 16384 + h * 8192 + tid * 8]);
    gl_lds16(aS + (size_t)(h * 128 + 64) * KDIM + T * 64,
             &LA[s * 16384 + h * 8192 + 4096 + tid * 8]);
  };
  auto stB2 = [&](int T, int s, int h) {
    gl_lds16(bS + (size_t)(h * 128)      * KDIM + T * 64,
             &LB[s * 16384 + h * 8192 + tid * 8]);
    gl_lds16(bS + (size_t)(h * 128 + 64) * KDIM + T * 64,
             &LB[s * 16384 + h * 8192 + 4096 + tid * 8]);
  };
  auto AF = [&](int s, int mf, int ks) {
    const int r = rAb + mf * 16;
    return *(const bf16x8*)&LA[s * 16384 + r * 64 + (((ks * 4 + g) ^ ax) << 3)];
  };
  auto BFr = [&](int s, int nf, int ks) {
    const int r = rBb + nf * 16;
    return *(const bf16x8*)&LB[s * 16384 + r * 64 + (((ks * 4 + g) ^ bx2) << 3)];
  };

  // prologue: tile 0 fully staged into slot 0 (8 loads/thread)
  stA2(0, 0, 0); stA2(0, 0, 1); stB2(0, 0, 0); stB2(0, 0, 1);

#define TILE8(T, VMC, STG)                                                     \
  {                                                                            \
    const int cur_ = (T) & 1, nxt_ = cur_ ^ 1;                                 \
    bf16x8 bfr[4], af[4];                                                      \
    /* ---- phase 0: stage A(T+1); validate tile T; quadrant mf0-3 ks0 ---- */ \
    if (STG) { stA2((T) + 1, nxt_, 0); stA2((T) + 1, nxt_, 1); }               \
    asm volatile("s_waitcnt vmcnt(" #VMC ")" ::: "memory");                    \
    __builtin_amdgcn_s_barrier();                                              \
    __builtin_amdgcn_sched_barrier(0);                                         \
    _Pragma("unroll") for (int nf = 0; nf < 4; ++nf) bfr[nf] = BFr(cur_, nf, 0); \
    _Pragma("unroll") for (int m = 0; m < 4; ++m)  af[m]  = AF(cur_, m, 0);    \
    __builtin_amdgcn_s_setprio(1);                                             \
    _Pragma("unroll") for (int m = 0; m < 4; ++m)                              \
      _Pragma("unroll") for (int nf = 0; nf < 4; ++nf)                         \
        acc[m][nf] = __builtin_amdgcn_mfma_f32_16x16x32_bf16(                  \
            af[m], bfr[nf], acc[m][nf], 0, 0, 0);                              \
    __builtin_amdgcn_s_setprio(0);                                             \
    __builtin_amdgcn_sched_barrier(0);                                         \
    __builtin_amdgcn_s_barrier();                                              \
    /* ---- phase 1: stage B(T+1); quadrant mf4-7 ks0 (bfr live) ---- */       \
    if (STG) { stB2((T) + 1, nxt_, 0); stB2((T) + 1, nxt_, 1); }               \
    _Pragma("unroll") for (int m = 0; m < 4; ++m) af[m] = AF(cur_, 4 + m, 0);  \
    __builtin_amdgcn_s_barrier();                                              \
    __builtin_amdgcn_sched_barrier(0);                                         \
    __builtin_amdgcn_s_setprio(1);                                             \
    _Pragma("unroll") for (int m = 0; m < 4; ++m)                              \
      _Pragma("unroll") for (int nf = 0; nf < 4; ++nf)                         \
        acc[4 + m][nf] = __builtin_amdgcn_mfma_f32_16x16x32_bf16(              \
            af[m], bfr[nf], acc[4 + m][nf], 0, 0, 0);                          \
    __builtin_amdgcn_s_setprio(0);                                             \
    __builtin_amdgcn_sched_barrier(0);                                         \
    __builtin_amdgcn_s_barrier();                                              \
    /* ---- phase 2: quadrant mf0-3 ks1 ---- */                                \
    _Pragma("unroll") for (int nf = 0; nf < 4; ++nf) bfr[nf] = BFr(cur_, nf, 1); \
    _Pragma("unroll") for (int m = 0; m < 4; ++m)  af[m]  = AF(cur_, m, 1);    \
    __builtin_amdgcn_s_barrier();                                              \
    __builtin_amdgcn_sched_barrier(0);                                         \
    __builtin_amdgcn_s_setprio(1);                                             \
    _Pragma("unroll") for (int m = 0; m < 4; ++m)                              \
      _Pragma("unroll") for (int nf = 0; nf < 4; ++nf)                         \
        acc[m][nf] = __builtin_amdgcn_mfma_f32_16x16x32_bf16(                  \
            af[m], bfr[nf], acc[m][nf], 0, 0, 0);                              \
    __builtin_amdgcn_s_setprio(0);                                             \
    __builtin_amdgcn_sched_barrier(0);                                         \
    __builtin_amdgcn_s_barrier();                                              \
    /* ---- phase 3: quadrant mf4-7 ks1 ---- */                                \
    _Pragma("unroll") for (int m = 0; m < 4; ++m) af[m] = AF(cur_, 4 + m, 1);  \
    __builtin_amdgcn_s_barrier();                                              \
    __builtin_amdgcn_sched_barrier(0);                                         \
    __builtin_amdgcn_s_setprio(1);                                             \
    _Pragma("unroll") for (int m = 0; m < 4; ++m)                              \
      _Pragma("unroll") for (int nf = 0; nf < 4; ++nf)                         \
        acc[4 + m][nf] = __builtin_amdgcn_mfma_f32_16x16x32_bf16(              \
            af[m], bfr[nf], acc[4 + m][nf], 0, 0, 0);                          \
    __builtin_amdgcn_s_setprio(0);                                             \
    __builtin_amdgcn_sched_barrier(0);                                         \
    __builtin_amdgcn_s_barrier();                                              \
  }

  for (int T = 0; T < 31; ++T) TILE8(T, 4, true)
  TILE8(31, 0, false)
#undef TILE8

  // epilogue (r9-verified layout): bias + scatter Q/K [b][h][s][d], V^T
  const int seg   = blockIdx.y >> 3;              // 0=Q 1=K 2=V
  const int nbase = (n0 & 2047) + wn * 64;
  const float* bias = (seg == 0) ? bq : (seg == 1) ? bkb : bv;
  float bvv[4];
#pragma unroll
  for (int nf = 0; nf < 4; ++nf) bvv[nf] = bias[nbase + nf * 16 + ln];

  if (seg < 2) {
    short* C = seg ? Ko : Qo;
#pragma unroll
    for (int mf = 0; mf < 8; ++mf) {
      const int mb = m0 + wm * 128 + mf * 16 + 4 * g;
      const int bb = mb >> 11, t = mb & (S_LEN - 1);
#pragma unroll
      for (int nf = 0; nf < 4; ++nf) {
        const int nl = nbase + nf * 16 + ln;
        const int h = nl >> 7, d = nl & 127;
#pragma unroll
        for (int e = 0; e < 4; ++e)
          C[((size_t)((bb * NHEAD + h) * S_LEN + t + e) << 7) + d] =
              f2bf(acc[mf][nf][e] + bvv[nf]);
      }
    }
  } else {
    short* C = Vo;
#pragma unroll
    for (int mf = 0; mf < 8; ++mf) {
      const int mb = m0 + wm * 128 + mf * 16 + 4 * g;
      const int bb = mb >> 11, t0 = mb & (S_LEN - 1);
#pragma unroll
      for (int nf = 0; nf < 4; ++nf) {
        const int nl = nbase + nf * 16 + ln;
        const int h = nl >> 7, d = nl & 127;
        short4v v;
#pragma unroll
        for (int e = 0; e < 4; ++e) v[e] = f2bf(acc[mf][nf][e] + bvv[nf]);
        *(short4v*)&C[((size_t)((bb * NHEAD + h) * HDIM + d)) * S_LEN + t0] = v;
      }
    }
  }
}

// ---------------- bf16 GEMM, C = A @ B^T + bias (BK=64, swizzled; r11) -------
// retained for the O-projection (512-block grid = 2 full rounds at 4/CU).
template<int KIND>
__global__ __launch_bounds__(256)
void gemm128(const short* __restrict__ A, const short* __restrict__ B,
             const float* __restrict__ bias0, const float* __restrict__ bias1,
             const float* __restrict__ bias2,
             void* __restrict__ O0, void* __restrict__ O1, void* __restrict__ O2)
{
  __shared__ __align__(16) short As[128 * 64];
  __shared__ __align__(16) short Bs[128 * 64];
  const int tid  = threadIdx.x;
  const int lane = tid & 63, wave = tid >> 6;
  const int ln = lane & 15, g = lane >> 4;
  const int wr = wave >> 1, wc = wave & 1;
  const int m0 = blockIdx.x * 128, n0 = blockIdx.y * 128;

  const int srow   = tid >> 3;
  const int schunk = (tid & 7) ^ (srow & 7);
  const short* aS = A + (size_t)(m0 + srow) * KDIM + schunk * 8;
  const short* bS = B + (size_t)(n0 + srow) * KDIM + schunk * 8;

  f32x4 acc[4][4] = {};

  for (int k0 = 0; k0 < KDIM; k0 += 64) {
    __syncthreads();
#pragma unroll
    for (int j = 0; j < 4; ++j) {
      gl_lds16(aS + k0 + j * (32 * KDIM), &As[j * 2048 + tid * 8]);
      gl_lds16(bS + k0 + j * (32 * KDIM), &Bs[j * 2048 + tid * 8]);
    }
    __syncthreads();

#pragma unroll
    for (int ks = 0; ks < 2; ++ks) {
      bf16x8 af[4], bfm[4];
#pragma unroll
      for (int i = 0; i < 4; ++i) {
        const int r = wr * 64 + i * 16 + ln;
        af[i] = *(const bf16x8*)&As[r * 64 + (((ks * 4 + g) ^ (r & 7)) << 3)];
      }
#pragma unroll
      for (int j2 = 0; j2 < 4; ++j2) {
        const int r = wc * 64 + j2 * 16 + ln;
        bfm[j2] = *(const bf16x8*)&Bs[r * 64 + (((ks * 4 + g) ^ (r & 7)) << 3)];
      }
#pragma unroll
      for (int i = 0; i < 4; ++i)
#pragma unroll
        for (int j2 = 0; j2 < 4; ++j2)
          acc[i][j2] = __builtin_amdgcn_mfma_f32_16x16x32_bf16(af[i], bfm[j2], acc[i][j2], 0, 0, 0);
    }
  }

  if constexpr (KIND == 1) {   // O-proj -> f32
    float* C = (float*)O0;
    float bvv[4];
#pragma unroll
    for (int j = 0; j < 4; ++j) bvv[j] = bias0[n0 + wc * 64 + j * 16 + ln];
#pragma unroll
    for (int i = 0; i < 4; ++i) {
      const int mb = m0 + wr * 64 + i * 16 + 4 * g;
#pragma unroll
      for (int j = 0; j < 4; ++j) {
        const int n = n0 + wc * 64 + j * 16 + ln;
#pragma unroll
        for (int e = 0; e < 4; ++e)
          C[(size_t)(mb + e) * HID + n] = acc[i][j][e] + bvv[j];
      }
    }
  }
}

// ---------------- RoPE in-place on Q,K ([b][h][s][d] bf16) -------------------
#define QSCALE 0.12752767502f   // (1/sqrt(128)) * log2(e)
__global__ __launch_bounds__(256)
void rope_kernel(short* __restrict__ Qb, short* __restrict__ Kb,
                 const int* __restrict__ pos_ids)
{
  const int row = blockIdx.x * 4 + (threadIdx.x >> 6);
  const int d   = threadIdx.x & 63;
  const int bh  = row >> 11, t = row & (S_LEN - 1);
  const int b   = bh >> 4;
  const float pos = (float)pos_ids[b * S_LEN + t];
  const float inv = exp2f((float)d * -0.20762050593f);  // log2(1e4)/64
  float s, c;
  sincosf(pos * inv, &s, &c);
  const size_t base = (size_t)row * HDIM;
  {
    float x1 = bf2f(Qb[base + d]), x2 = bf2f(Qb[base + d + 64]);
    Qb[base + d]      = f2bf((x1 * c - x2 * s) * QSCALE);
    Qb[base + d + 64] = f2bf((x2 * c + x1 * s) * QSCALE);
  }
  {
    float x1 = bf2f(Kb[base + d]), x2 = bf2f(Kb[base + d + 64]);
    Kb[base + d]      = f2bf(x1 * c - x2 * s);
    Kb[base + d + 64] = f2bf(x2 * c + x1 * s);
  }
}

// ---------------- flash attention: 4-wave 32x32 swapped, merged halves (r22) -
__global__ __launch_bounds__(256, 2)
void attn_kernel(const short* __restrict__ Qb, const short* __restrict__ Kb,
                 const short* __restrict__ Vt, short* __restrict__ AO)
{
  __shared__ __align__(16) short Ks[128 * 128];   // [kv][d]
  __shared__ __align__(16) short Vs[128 * 128];   // [d][kv]
  const int tid  = threadIdx.x;
  const int wave = tid >> 6, lane = tid & 63;
  const int lq = lane & 31, lh = lane >> 5;
  const int bid = blockIdx.x;
  const int bh  = bid & 31;
  const int grp = bid >> 5;
  const int yt  = (grp & 7) ^ ((grp & 8) ? 15 : 0);
  const int qw  = yt * 128 + wave * 32;
  const int q   = qw + lq;

  const short* Kbh = Kb + (size_t)bh * (S_LEN * HDIM);
  const short* Vbh = Vt + (size_t)bh * (S_LEN * HDIM);
  const int sw   = ((tid & 15) ^ ((tid >> 4) & 7)) << 3;
  const int kOff = (tid >> 4) * HDIM + sw;
  const int vOff = (tid >> 4) * S_LEN + sw;

  bf16x8 qf[8];
#pragma unroll
  for (int kk = 0; kk < 8; ++kk)
    qf[kk] = *(const bf16x8*)&Qb[((size_t)bh * S_LEN + q) * HDIM + kk * 16 + lh * 8];

  f32x16 o[4] = {};
  float m_s = -3.0e38f, l_s = 0.f;

  for (int kvt = 0; kvt <= yt; ++kvt) {
    const int kv0 = kvt * 128;
    __syncthreads();
#pragma unroll
    for (int p = 0; p < 8; ++p) {
      gl_lds16(Kbh + (size_t)kv0 * HDIM + kOff + p * (16 * HDIM), &Ks[p * 2048 + tid * 8]);
      gl_lds16(Vbh + kv0 + vOff + p * (16 * S_LEN),               &Vs[p * 2048 + tid * 8]);
    }
    __syncthreads();

    f32x16 sfr[4] = {};
    __builtin_amdgcn_s_setprio(1);
#pragma unroll
    for (int kk = 0; kk < 8; ++kk) {
#pragma unroll
      for (int nt = 0; nt < 4; ++nt) {
        const int row = nt * 32 + lq;
        bf16x8 ak = *(const bf16x8*)&Ks[(row * 128 + kk * 16 + lh * 8) ^ ((row & 7) << 3)];
        sfr[nt] = __builtin_amdgcn_mfma_f32_32x32x16_bf16(ak, qf[kk], sfr[nt], 0, 0, 0);
      }
    }
    __builtin_amdgcn_s_setprio(0);

    if (kvt == yt) {
#pragma unroll
      for (int nt = 0; nt < 4; ++nt) {
        const int kvb = kv0 + nt * 32 + 4 * lh;
#pragma unroll
        for (int r = 0; r < 16; ++r) {
          const int kv = kvb + (r & 3) + 8 * (r >> 2);
          if (kv > q) sfr[nt][r] = -3.0e38f;
        }
      }
    }

    float rmax = -3.0e38f;
#pragma unroll
    for (int nt = 0; nt < 4; ++nt)
#pragma unroll
      for (int r = 0; r < 16; ++r) rmax = fmaxf(rmax, sfr[nt][r]);
    rmax = fmaxf(rmax, __shfl_xor(rmax, 32));

    if (__any(rmax > m_s + 8.0f)) {
      const float nm = fmaxf(m_s, rmax);
      const float corr = exp2f(m_s - nm);
      m_s = nm;
      l_s *= corr;
#pragma unroll
      for (int dt = 0; dt < 4; ++dt)
#pragma unroll
        for (int r = 0; r < 16; ++r) o[dt][r] *= corr;
    }

    float ps = 0.f;
#pragma unroll
    for (int nt = 0; nt < 4; ++nt)
#pragma unroll
      for (int r = 0; r < 16; ++r) {
        const float pv = exp2f(sfr[nt][r] - m_s);
        sfr[nt][r] = pv;
        ps += pv;
      }
    l_s += ps;

    bf16x8 pa[8];
#pragma unroll
    for (int kk = 0; kk < 8; ++kk) {
      const int nt = kk >> 1, c8 = (kk & 1) * 8;
      unsigned w0, w1, w2, w3;
      asm("v_cvt_pk_bf16_f32 %0, %1, %2" : "=v"(w0) : "v"(sfr[nt][c8 + 0]), "v"(sfr[nt][c8 + 1]));
      asm("v_cvt_pk_bf16_f32 %0, %1, %2" : "=v"(w1) : "v"(sfr[nt][c8 + 2]), "v"(sfr[nt][c8 + 3]));
      asm("v_cvt_pk_bf16_f32 %0, %1, %2" : "=v"(w2) : "v"(sfr[nt][c8 + 4]), "v"(sfr[nt][c8 + 5]));
      asm("v_cvt_pk_bf16_f32 %0, %1, %2" : "=v"(w3) : "v"(sfr[nt][c8 + 6]), "v"(sfr[nt][c8 + 7]));
      asm volatile("v_permlane32_swap_b32 %0, %1" : "+v"(w0), "+v"(w2));
      asm volatile("v_permlane32_swap_b32 %0, %1" : "+v"(w1), "+v"(w3));
      uint4v u; u[0] = w0; u[1] = w1; u[2] = w2; u[3] = w3;
      pa[kk] = __builtin_bit_cast(bf16x8, u);
    }

    __builtin_amdgcn_s_setprio(1);
#pragma unroll
    for (int kk = 0; kk < 8; ++kk) {
#pragma unroll
      for (int dt = 0; dt < 4; ++dt) {
        const int row = dt * 32 + lq;
        bf16x8 av = *(const bf16x8*)&Vs[(row * 128 + kk * 16 + lh * 8) ^ ((row & 7) << 3)];
        o[dt] = __builtin_amdgcn_mfma_f32_32x32x16_bf16(av, pa[kk], o[dt], 0, 0, 0);
      }
    }
    __builtin_amdgcn_s_setprio(0);
  }

  l_s += __shfl_xor(l_s, 32);
  const float inv = 1.0f / l_s;
  const int b = bh >> 4, hh = bh & 15;
  short* dst = &AO[((size_t)b * S_LEN + q) * HID + hh * HDIM];
#pragma unroll
  for (int dt = 0; dt < 4; ++dt) {
#pragma unroll
    for (int rq = 0; rq < 4; ++rq) {
      short4v v4;
#pragma unroll
      for (int e = 0; e < 4; ++e) v4[e] = f2bf(o[dt][rq * 4 + e] * inv);
      *(short4v*)&dst[dt * 32 + rq * 8 + 4 * lh] = v4;
    }
  }
}

extern "C" void kernel_launch(void* const* d_in, const int* in_sizes, int n_in,
                              void* d_out, int out_size, void* d_ws, size_t ws_size,
                              hipStream_t stream)
{
  const float* hs = (const float*)d_in[0];
  const float* wq = (const float*)d_in[1];
  const float* bq = (const float*)d_in[2];
  const float* wk = (const float*)d_in[3];
  const float* bk = (const float*)d_in[4];
  const float* wv = (const float*)d_in[5];
  const float* bv = (const float*)d_in[6];
  const float* wo = (const float*)d_in[7];
  const float* bo = (const float*)d_in[8];
  const int*  pos = (const int*)d_in[10];
  float* out = (float*)d_out;

  const size_t TSZ = (size_t)BATCH * NHEAD * S_LEN * HDIM;  // 8388608 elems
  short* Qb   = (short*)d_ws;
  short* Kb   = Qb + TSZ;
  short* Vt   = Kb + TSZ;
  short* hsb  = Vt + TSZ;        // hs bf16; reused as AO after QKV GEMM
  short* AO   = hsb;
  short* Wqkv = hsb + TSZ;
  short* wob  = Wqkv + 12582912;

  convert_all<<<2048, 256, 0, stream>>>(hs, wq, wk, wv, wo, hsb, Wqkv, wob);
  gemm256_8p<<<dim3(16, 24), 512, 0, stream>>>(hsb, Wqkv, bq, bk, bv, Qb, Kb, Vt);
  rope_kernel<<<(BATCH * NHEAD * S_LEN) / 4, 256, 0, stream>>>(Qb, Kb, pos);
  attn_kernel<<<512, 256, 0, stream>>>(Qb, Kb, Vt, AO);
  gemm128<1><<<dim3(32, 16), 256, 0, stream>>>(AO, wob, bo, nullptr, nullptr, out, nullptr, nullptr);
}

// Round 25
// 248.668 us; speedup vs baseline: 1.1563x; 1.1563x over previous
//
#include <hip/hip_runtime.h>

#define S_LEN 2048
#define HID   2048
#define NHEAD 16
#define HDIM  128
#define BATCH 2
#define KDIM  2048

using bf16x8  = __attribute__((ext_vector_type(8))) short;
using f32x4   = __attribute__((ext_vector_type(4))) float;
using f32x16  = __attribute__((ext_vector_type(16))) float;
using short4v = __attribute__((ext_vector_type(4))) short;
using uint4v  = __attribute__((ext_vector_type(4))) unsigned;

__device__ __forceinline__ short f2bf(float f) {
  union { float f; unsigned u; } v; v.f = f;
  unsigned r = v.u + 0x7fffu + ((v.u >> 16) & 1u);
  return (short)(r >> 16);
}
__device__ __forceinline__ float bf2f(short s) {
  union { unsigned u; float f; } v;
  v.u = ((unsigned)(unsigned short)s) << 16;
  return v.f;
}

// async global->LDS, 16B per lane. LDS dest must be wave-uniform base + lane*16.
__device__ __forceinline__ void gl_lds16(const void* g, void* l) {
  __builtin_amdgcn_global_load_lds(
      (const __attribute__((address_space(1))) void*)g,
      (__attribute__((address_space(3))) void*)l, 16, 0, 0);
}

// ---------------- convert: hs, wq, wk, wv, wo  f32 -> bf16 -------------------
__global__ __launch_bounds__(256)
void convert_all(const float* __restrict__ hs, const float* __restrict__ wq,
                 const float* __restrict__ wk, const float* __restrict__ wv,
                 const float* __restrict__ wo,
                 short* __restrict__ hsb, short* __restrict__ wqkv,
                 short* __restrict__ wob)
{
  const int base = blockIdx.x * 256 + threadIdx.x;
#pragma unroll
  for (int it = 0; it < 6; ++it) {
    int j = base + it * 524288;
    const float* src; short* dst;
    if (j < 1048576)      { src = hs; dst = hsb; }
    else if (j < 1572864) { j -= 1048576; src = wq; dst = wqkv; }
    else if (j < 2097152) { j -= 1572864; src = wk; dst = wqkv + 4194304; }
    else if (j < 2621440) { j -= 2097152; src = wv; dst = wqkv + 8388608; }
    else                  { j -= 2621440; src = wo; dst = wob; }
    f32x4 a = ((const f32x4*)src)[2 * j];
    f32x4 b = ((const f32x4*)src)[2 * j + 1];
    bf16x8 o;
    o[0]=f2bf(a[0]); o[1]=f2bf(a[1]); o[2]=f2bf(a[2]); o[3]=f2bf(a[3]);
    o[4]=f2bf(b[0]); o[5]=f2bf(b[1]); o[6]=f2bf(b[2]); o[7]=f2bf(b[3]);
    ((bf16x8*)dst)[j] = o;
  }
}

// ---------------- bf16 GEMM, C = A @ B^T + bias (BK=64, swizzled; r11) -------
template<int KIND>
__global__ __launch_bounds__(256)
void gemm128(const short* __restrict__ A, const short* __restrict__ B,
             const float* __restrict__ bias0, const float* __restrict__ bias1,
             const float* __restrict__ bias2,
             void* __restrict__ O0, void* __restrict__ O1, void* __restrict__ O2)
{
  __shared__ __align__(16) short As[128 * 64];
  __shared__ __align__(16) short Bs[128 * 64];
  const int tid  = threadIdx.x;
  const int lane = tid & 63, wave = tid >> 6;
  const int ln = lane & 15, g = lane >> 4;
  const int wr = wave >> 1, wc = wave & 1;
  const int m0 = blockIdx.x * 128, n0 = blockIdx.y * 128;

  const int srow   = tid >> 3;
  const int schunk = (tid & 7) ^ (srow & 7);
  const short* aS = A + (size_t)(m0 + srow) * KDIM + schunk * 8;
  const short* bS = B + (size_t)(n0 + srow) * KDIM + schunk * 8;

  f32x4 acc[4][4] = {};

  for (int k0 = 0; k0 < KDIM; k0 += 64) {
    __syncthreads();
#pragma unroll
    for (int j = 0; j < 4; ++j) {
      gl_lds16(aS + k0 + j * (32 * KDIM), &As[j * 2048 + tid * 8]);
      gl_lds16(bS + k0 + j * (32 * KDIM), &Bs[j * 2048 + tid * 8]);
    }
    __syncthreads();

#pragma unroll
    for (int ks = 0; ks < 2; ++ks) {
      bf16x8 af[4], bfm[4];
#pragma unroll
      for (int i = 0; i < 4; ++i) {
        const int r = wr * 64 + i * 16 + ln;
        af[i] = *(const bf16x8*)&As[r * 64 + (((ks * 4 + g) ^ (r & 7)) << 3)];
      }
#pragma unroll
      for (int j2 = 0; j2 < 4; ++j2) {
        const int r = wc * 64 + j2 * 16 + ln;
        bfm[j2] = *(const bf16x8*)&Bs[r * 64 + (((ks * 4 + g) ^ (r & 7)) << 3)];
      }
#pragma unroll
      for (int i = 0; i < 4; ++i)
#pragma unroll
        for (int j2 = 0; j2 < 4; ++j2)
          acc[i][j2] = __builtin_amdgcn_mfma_f32_16x16x32_bf16(af[i], bfm[j2], acc[i][j2], 0, 0, 0);
    }
  }

  if constexpr (KIND == 0) {
    const int seg   = n0 >> 11;
    const int nbase = (n0 & 2047) + wc * 64;
    const float* bias = (seg == 0) ? bias0 : (seg == 1) ? bias1 : bias2;
    float bvv[4];
#pragma unroll
    for (int j = 0; j < 4; ++j) bvv[j] = bias[nbase + j * 16 + ln];
    if (seg < 2) {           // Q,K -> [b][h][s][d] bf16
      short* C = (short*)(seg ? O1 : O0);
#pragma unroll
      for (int i = 0; i < 4; ++i) {
        const int mb = m0 + wr * 64 + i * 16 + 4 * g;
#pragma unroll
        for (int j = 0; j < 4; ++j) {
          const int nl = nbase + j * 16 + ln;
          const int h = nl >> 7, d = nl & 127;
#pragma unroll
          for (int e = 0; e < 4; ++e) {
            const int m = mb + e, bb = m >> 11, t = m & (S_LEN - 1);
            C[((size_t)((bb * NHEAD + h) * S_LEN + t) << 7) + d] = f2bf(acc[i][j][e] + bvv[j]);
          }
        }
      }
    } else {                 // V -> transposed [b][h][d][s] bf16
      short* C = (short*)O2;
#pragma unroll
      for (int i = 0; i < 4; ++i) {
        const int mb = m0 + wr * 64 + i * 16 + 4 * g;
        const int bb = mb >> 11, t0 = mb & (S_LEN - 1);
#pragma unroll
        for (int j = 0; j < 4; ++j) {
          const int nl = nbase + j * 16 + ln;
          const int h = nl >> 7, d = nl & 127;
          short4v v;
#pragma unroll
          for (int e = 0; e < 4; ++e) v[e] = f2bf(acc[i][j][e] + bvv[j]);
          *(short4v*)&C[((size_t)((bb * NHEAD + h) * HDIM + d)) * S_LEN + t0] = v;
        }
      }
    }
  } else {                   // O-proj -> f32
    float* C = (float*)O0;
    float bvv[4];
#pragma unroll
    for (int j = 0; j < 4; ++j) bvv[j] = bias0[n0 + wc * 64 + j * 16 + ln];
#pragma unroll
    for (int i = 0; i < 4; ++i) {
      const int mb = m0 + wr * 64 + i * 16 + 4 * g;
#pragma unroll
      for (int j = 0; j < 4; ++j) {
        const int n = n0 + wc * 64 + j * 16 + ln;
#pragma unroll
        for (int e = 0; e < 4; ++e)
          C[(size_t)(mb + e) * HID + n] = acc[i][j][e] + bvv[j];
      }
    }
  }
}

// ---------------- RoPE in-place on Q,K ([b][h][s][d] bf16) -------------------
#define QSCALE 0.12752767502f   // (1/sqrt(128)) * log2(e)
__global__ __launch_bounds__(256)
void rope_kernel(short* __restrict__ Qb, short* __restrict__ Kb,
                 const int* __restrict__ pos_ids)
{
  const int row = blockIdx.x * 4 + (threadIdx.x >> 6);
  const int d   = threadIdx.x & 63;
  const int bh  = row >> 11, t = row & (S_LEN - 1);
  const int b   = bh >> 4;
  const float pos = (float)pos_ids[b * S_LEN + t];
  const float inv = exp2f((float)d * -0.20762050593f);  // log2(1e4)/64
  float s, c;
  sincosf(pos * inv, &s, &c);
  const size_t base = (size_t)row * HDIM;
  {
    float x1 = bf2f(Qb[base + d]), x2 = bf2f(Qb[base + d + 64]);
    Qb[base + d]      = f2bf((x1 * c - x2 * s) * QSCALE);
    Qb[base + d + 64] = f2bf((x2 * c + x1 * s) * QSCALE);
  }
  {
    float x1 = bf2f(Kb[base + d]), x2 = bf2f(Kb[base + d + 64]);
    Kb[base + d]      = f2bf(x1 * c - x2 * s);
    Kb[base + d + 64] = f2bf(x2 * c + x1 * s);
  }
}

// ---------------- flash attention: 4-wave 32x32 swapped, merged halves (r22) -
__global__ __launch_bounds__(256, 2)
void attn_kernel(const short* __restrict__ Qb, const short* __restrict__ Kb,
                 const short* __restrict__ Vt, short* __restrict__ AO)
{
  __shared__ __align__(16) short Ks[128 * 128];   // [kv][d]
  __shared__ __align__(16) short Vs[128 * 128];   // [d][kv]
  const int tid  = threadIdx.x;
  const int wave = tid >> 6, lane = tid & 63;
  const int lq = lane & 31, lh = lane >> 5;
  const int bid = blockIdx.x;
  const int bh  = bid & 31;
  const int grp = bid >> 5;
  const int yt  = (grp & 7) ^ ((grp & 8) ? 15 : 0);
  const int qw  = yt * 128 + wave * 32;
  const int q   = qw + lq;

  const short* Kbh = Kb + (size_t)bh * (S_LEN * HDIM);
  const short* Vbh = Vt + (size_t)bh * (S_LEN * HDIM);
  const int sw   = ((tid & 15) ^ ((tid >> 4) & 7)) << 3;
  const int kOff = (tid >> 4) * HDIM + sw;
  const int vOff = (tid >> 4) * S_LEN + sw;

  bf16x8 qf[8];
#pragma unroll
  for (int kk = 0; kk < 8; ++kk)
    qf[kk] = *(const bf16x8*)&Qb[((size_t)bh * S_LEN + q) * HDIM + kk * 16 + lh * 8];

  f32x16 o[4] = {};
  float m_s = -3.0e38f, l_s = 0.f;

  for (int kvt = 0; kvt <= yt; ++kvt) {
    const int kv0 = kvt * 128;
    __syncthreads();
#pragma unroll
    for (int p = 0; p < 8; ++p) {
      gl_lds16(Kbh + (size_t)kv0 * HDIM + kOff + p * (16 * HDIM), &Ks[p * 2048 + tid * 8]);
      gl_lds16(Vbh + kv0 + vOff + p * (16 * S_LEN),               &Vs[p * 2048 + tid * 8]);
    }
    __syncthreads();

    f32x16 sfr[4] = {};
    __builtin_amdgcn_s_setprio(1);
#pragma unroll
    for (int kk = 0; kk < 8; ++kk) {
#pragma unroll
      for (int nt = 0; nt < 4; ++nt) {
        const int row = nt * 32 + lq;
        bf16x8 ak = *(const bf16x8*)&Ks[(row * 128 + kk * 16 + lh * 8) ^ ((row & 7) << 3)];
        sfr[nt] = __builtin_amdgcn_mfma_f32_32x32x16_bf16(ak, qf[kk], sfr[nt], 0, 0, 0);
      }
    }
    __builtin_amdgcn_s_setprio(0);

    if (kvt == yt) {
#pragma unroll
      for (int nt = 0; nt < 4; ++nt) {
        const int kvb = kv0 + nt * 32 + 4 * lh;
#pragma unroll
        for (int r = 0; r < 16; ++r) {
          const int kv = kvb + (r & 3) + 8 * (r >> 2);
          if (kv > q) sfr[nt][r] = -3.0e38f;
        }
      }
    }

    float rmax = -3.0e38f;
#pragma unroll
    for (int nt = 0; nt < 4; ++nt)
#pragma unroll
      for (int r = 0; r < 16; ++r) rmax = fmaxf(rmax, sfr[nt][r]);
    rmax = fmaxf(rmax, __shfl_xor(rmax, 32));

    if (__any(rmax > m_s + 8.0f)) {
      const float nm = fmaxf(m_s, rmax);
      const float corr = exp2f(m_s - nm);
      m_s = nm;
      l_s *= corr;
#pragma unroll
      for (int dt = 0; dt < 4; ++dt)
#pragma unroll
        for (int r = 0; r < 16; ++r) o[dt][r] *= corr;
    }

    float ps = 0.f;
#pragma unroll
    for (int nt = 0; nt < 4; ++nt)
#pragma unroll
      for (int r = 0; r < 16; ++r) {
        const float pv = exp2f(sfr[nt][r] - m_s);
        sfr[nt][r] = pv;
        ps += pv;
      }
    l_s += ps;

    bf16x8 pa[8];
#pragma unroll
    for (int kk = 0; kk < 8; ++kk) {
      const int nt = kk >> 1, c8 = (kk & 1) * 8;
      unsigned w0, w1, w2, w3;
      asm("v_cvt_pk_bf16_f32 %0, %1, %2" : "=v"(w0) : "v"(sfr[nt][c8 + 0]), "v"(sfr[nt][c8 + 1]));
      asm("v_cvt_pk_bf16_f32 %0, %1, %2" : "=v"(w1) : "v"(sfr[nt][c8 + 2]), "v"(sfr[nt][c8 + 3]));
      asm("v_cvt_pk_bf16_f32 %0, %1, %2" : "=v"(w2) : "v"(sfr[nt][c8 + 4]), "v"(sfr[nt][c8 + 5]));
      asm("v_cvt_pk_bf16_f32 %0, %1, %2" : "=v"(w3) : "v"(sfr[nt][c8 + 6]), "v"(sfr[nt][c8 + 7]));
      asm volatile("v_permlane32_swap_b32 %0, %1" : "+v"(w0), "+v"(w2));
      asm volatile("v_permlane32_swap_b32 %0, %1" : "+v"(w1), "+v"(w3));
      uint4v u; u[0] = w0; u[1] = w1; u[2] = w2; u[3] = w3;
      pa[kk] = __builtin_bit_cast(bf16x8, u);
    }

    __builtin_amdgcn_s_setprio(1);
#pragma unroll
    for (int kk = 0; kk < 8; ++kk) {
#pragma unroll
      for (int dt = 0; dt < 4; ++dt) {
        const int row = dt * 32 + lq;
        bf16x8 av = *(const bf16x8*)&Vs[(row * 128 + kk * 16 + lh * 8) ^ ((row & 7) << 3)];
        o[dt] = __builtin_amdgcn_mfma_f32_32x32x16_bf16(av, pa[kk], o[dt], 0, 0, 0);
      }
    }
    __builtin_amdgcn_s_setprio(0);
  }

  l_s += __shfl_xor(l_s, 32);
  const float inv = 1.0f / l_s;
  const int b = bh >> 4, hh = bh & 15;
  short* dst = &AO[((size_t)b * S_LEN + q) * HID + hh * HDIM];
#pragma unroll
  for (int dt = 0; dt < 4; ++dt) {
#pragma unroll
    for (int rq = 0; rq < 4; ++rq) {
      short4v v4;
#pragma unroll
      for (int e = 0; e < 4; ++e) v4[e] = f2bf(o[dt][rq * 4 + e] * inv);
      *(short4v*)&dst[dt * 32 + rq * 8 + 4 * lh] = v4;
    }
  }
}

extern "C" void kernel_launch(void* const* d_in, const int* in_sizes, int n_in,
                              void* d_out, int out_size, void* d_ws, size_t ws_size,
                              hipStream_t stream)
{
  const float* hs = (const float*)d_in[0];
  const float* wq = (const float*)d_in[1];
  const float* bq = (const float*)d_in[2];
  const float* wk = (const float*)d_in[3];
  const float* bk = (const float*)d_in[4];
  const float* wv = (const float*)d_in[5];
  const float* bv = (const float*)d_in[6];
  const float* wo = (const float*)d_in[7];
  const float* bo = (const float*)d_in[8];
  const int*  pos = (const int*)d_in[10];
  float* out = (float*)d_out;

  const size_t TSZ = (size_t)BATCH * NHEAD * S_LEN * HDIM;  // 8388608 elems
  short* Qb   = (short*)d_ws;
  short* Kb   = Qb + TSZ;
  short* Vt   = Kb + TSZ;
  short* hsb  = Vt + TSZ;        // hs bf16; reused as AO after QKV GEMM
  short* AO   = hsb;
  short* Wqkv = hsb + TSZ;
  short* wob  = Wqkv + 12582912;

  convert_all<<<2048, 256, 0, stream>>>(hs, wq, wk, wv, wo, hsb, Wqkv, wob);
  gemm128<0><<<dim3(32, 48), 256, 0, stream>>>(hsb, Wqkv, bq, bk, bv, Qb, Kb, Vt);
  rope_kernel<<<(BATCH * NHEAD * S_LEN) / 4, 256, 0, stream>>>(Qb, Kb, pos);
  attn_kernel<<<512, 256, 0, stream>>>(Qb, Kb, Vt, AO);
  gemm128<1><<<dim3(32, 16), 256, 0, stream>>>(AO, wob, bo, nullptr, nullptr, out, nullptr, nullptr);
}